// Round 1
// baseline (585.530 us; speedup 1.0000x reference)
//
#include <hip/hip_runtime.h>
#include <math.h>

// Tropical bottleneck network, fp32.
// Core op: Y[b,i] = red_j (X[b,j] + W[i,j]) (+ bias[i]) , red = min or max,
// optionally combined with an elementwise shortcut tensor (min or max).
//
// Tiled semiring matmul: BM=64 x BN=64 output tile, BK=32 K-chunks,
// 256 threads (16x16), 4x4 register micro-tile per thread.

#define BM 64
#define BN 64
#define BK 32
#define PAD 4   // keeps 16B alignment for float4 LDS reads, breaks bank conflicts

// IS_MAX: 0 = min-reduction, 1 = max-reduction
// COMBINE: 0 = none, 1 = Y = min(Y, extra), 2 = Y = max(Y, extra)
template<int IS_MAX, int COMBINE>
__global__ __launch_bounds__(256) void semimm(
    const float* __restrict__ X,      // [B, IN]
    const float* __restrict__ W,      // [OUT, IN]
    const float* __restrict__ bias,   // [OUT] or nullptr
    const float* __restrict__ extra,  // [B, OUT] or nullptr
    float* __restrict__ Y,            // [B, OUT]
    int B, int IN, int OUT)
{
    __shared__ __align__(16) float Xs[BK][BM + PAD];
    __shared__ __align__(16) float Ws[BK][BN + PAD];

    const int tid = threadIdx.x;      // 0..255
    const int tx  = tid & 15;         // column group (n)
    const int ty  = tid >> 4;         // row group (m)
    const int bm  = blockIdx.x * BM;
    const int bn  = blockIdx.y * BN;

    const float INIT = IS_MAX ? -INFINITY : INFINITY;
    float acc[4][4];
#pragma unroll
    for (int i = 0; i < 4; ++i)
#pragma unroll
        for (int j = 0; j < 4; ++j) acc[i][j] = INIT;

    // loader mapping: 32 lanes along k (coalesced global reads), 8 row groups
    const int lk = tid & 31;
    const int lm = tid >> 5;          // 0..7

    for (int k0 = 0; k0 < IN; k0 += BK) {
#pragma unroll
        for (int r = 0; r < BM; r += 8) {
            int m = r + lm;
            Xs[lk][m] = X[(bm + m) * IN + k0 + lk];
        }
#pragma unroll
        for (int r = 0; r < BN; r += 8) {
            int n = r + lm;
            Ws[lk][n] = W[(bn + n) * IN + k0 + lk];
        }
        __syncthreads();

#pragma unroll
        for (int k = 0; k < BK; ++k) {
            float4 A  = *(const float4*)(&Xs[k][ty * 4]);
            float4 Wv = *(const float4*)(&Ws[k][tx * 4]);
            const float aa[4] = {A.x, A.y, A.z, A.w};
            const float ww[4] = {Wv.x, Wv.y, Wv.z, Wv.w};
#pragma unroll
            for (int mi = 0; mi < 4; ++mi)
#pragma unroll
                for (int ni = 0; ni < 4; ++ni) {
                    float v = aa[mi] + ww[ni];
                    acc[mi][ni] = IS_MAX ? fmaxf(acc[mi][ni], v)
                                         : fminf(acc[mi][ni], v);
                }
        }
        __syncthreads();
    }

    // epilogue: bias + optional combine, float4 stores
#pragma unroll
    for (int mi = 0; mi < 4; ++mi) {
        int row = bm + ty * 4 + mi;
        int col = bn + tx * 4;
        float4 v = make_float4(acc[mi][0], acc[mi][1], acc[mi][2], acc[mi][3]);
        if (bias) {
            float4 bb = *(const float4*)(&bias[col]);
            v.x += bb.x; v.y += bb.y; v.z += bb.z; v.w += bb.w;
        }
        if (COMBINE == 1) {
            float4 e = *(const float4*)(&extra[row * OUT + col]);
            v.x = fminf(v.x, e.x); v.y = fminf(v.y, e.y);
            v.z = fminf(v.z, e.z); v.w = fminf(v.w, e.w);
        } else if (COMBINE == 2) {
            float4 e = *(const float4*)(&extra[row * OUT + col]);
            v.x = fmaxf(v.x, e.x); v.y = fmaxf(v.y, e.y);
            v.z = fmaxf(v.z, e.z); v.w = fmaxf(v.w, e.w);
        }
        *(float4*)(&Y[row * OUT + col]) = v;
    }
}

extern "C" void kernel_launch(void* const* d_in, const int* in_sizes, int n_in,
                              void* d_out, int out_size, void* d_ws, size_t ws_size,
                              hipStream_t stream) {
    const float* x      = (const float*)d_in[0];
    const float* l1_w1  = (const float*)d_in[1];
    const float* l1_w2  = (const float*)d_in[2];
    const float* l1_b2  = (const float*)d_in[3];
    const float* l2_w1  = (const float*)d_in[4];
    const float* l2_w2  = (const float*)d_in[5];
    const float* l2_b2  = (const float*)d_in[6];
    const float* l3_w1  = (const float*)d_in[7];
    const float* l3_w2  = (const float*)d_in[8];
    const float* l3_b2  = (const float*)d_in[9];
    const float* l4_w1  = (const float*)d_in[10];
    const float* l4_w2  = (const float*)d_in[11];
    const float* l4_b2  = (const float*)d_in[12];
    const float* l4_sw1 = (const float*)d_in[13];
    const float* l4_sw2 = (const float*)d_in[14];
    const float* l4_sb2 = (const float*)d_in[15];
    const float* sc_w1  = (const float*)d_in[16];
    const float* sc_w2  = (const float*)d_in[17];
    const float* sc_b2  = (const float*)d_in[18];

    float* out = (float*)d_out;
    float* ws  = (float*)d_ws;

    const int B = 1024, IN = 256, OUT = 512;

    // workspace layout (floats): W0 [1024*512], W1 [1024*256], W2 [1024*256], W3 [1024*512]
    float* W0 = ws;
    float* W1 = W0 + B * OUT;
    float* W2 = W1 + B * IN;
    float* W3 = W2 + B * IN;
    (void)ws_size; (void)n_in; (void)in_sizes; (void)out_size;

    dim3 blk(256);
    dim3 gS(B / BM, IN / BN);    // 16 x 4  (OUT=256 stages)
    dim3 gL(B / BM, OUT / BN);   // 16 x 8  (OUT=512 stages)

    // layer 1..3 (in==out==256, shortcut = input)
    semimm<0,0><<<gS, blk, 0, stream>>>(x,  l1_w1, nullptr, nullptr, W0, B, IN, IN);
    semimm<1,1><<<gS, blk, 0, stream>>>(W0, l1_w2, l1_b2,   x,       W1, B, IN, IN);
    semimm<0,0><<<gS, blk, 0, stream>>>(W1, l2_w1, nullptr, nullptr, W0, B, IN, IN);
    semimm<1,1><<<gS, blk, 0, stream>>>(W0, l2_w2, l2_b2,   W1,      W2, B, IN, IN);
    semimm<0,0><<<gS, blk, 0, stream>>>(W2, l3_w1, nullptr, nullptr, W0, B, IN, IN);
    semimm<1,1><<<gS, blk, 0, stream>>>(W0, l3_w2, l3_b2,   W2,      W1, B, IN, IN); // x3 -> W1

    // layer 4 main path: t4m = minplus(x3, l4_w1); o4m = maxbplus(t4m, l4_w2, l4_b2)
    semimm<0,0><<<gL, blk, 0, stream>>>(W1, l4_w1, nullptr, nullptr, W0, B, IN,  OUT);
    semimm<1,0><<<gL, blk, 0, stream>>>(W0, l4_w2, l4_b2,   nullptr, W3, B, OUT, OUT);
    // layer 4 shortcut path, combined (min) with main
    semimm<0,0><<<gL, blk, 0, stream>>>(W1, l4_sw1, nullptr, nullptr, W0,  B, IN,  OUT);
    semimm<1,1><<<gL, blk, 0, stream>>>(W0, l4_sw2, l4_sb2,  W3,      out, B, OUT, OUT);

    // bottleneck shortcut from original x, combined (max) with layer-4 output
    semimm<0,0><<<gL, blk, 0, stream>>>(x,  sc_w1, nullptr, nullptr, W0,  B, IN,  OUT);
    semimm<1,2><<<gL, blk, 0, stream>>>(W0, sc_w2, sc_b2,   out,     out, B, OUT, OUT);
}

// Round 2
// 320.713 us; speedup vs baseline: 1.8257x; 1.8257x over previous
//
#include <hip/hip_runtime.h>
#include <math.h>

// Tropical bottleneck network, fp32 — LDS-free scalar-broadcast design.
//
// Core op on TRANSPOSED activations: Yt[i][b] = red_k(Xt[k][b] + W[i][k]) (+bias[i]),
// optionally combined elementwise with Et[i][b].
// Lanes = 64 consecutive b (coalesced activation access); W[i][k] is wave-uniform
// (SGPR / scalar-load path); each wave computes NI=4 output rows.

#define B_ALL 1024

__device__ __forceinline__ float r2min(float a, float b) { return fminf(a, b); }
__device__ __forceinline__ float r2max(float a, float b) { return fmaxf(a, b); }

// IS_MAX: 0 = min-reduction, 1 = max-reduction (max stages also add bias)
// COMBINE: 0 = none, 1 = Y = min(Y, extra), 2 = Y = max(Y, extra)
template<int IS_MAX, int COMBINE>
__global__ __launch_bounds__(256) void tsemi(
    const float* __restrict__ Xt,    // [K][B]
    const float* __restrict__ W,     // [OUT][K]  (original row-major weights)
    const float* __restrict__ bias,  // [OUT] (used when IS_MAX)
    const float* __restrict__ Et,    // [OUT][B] or nullptr
    float* __restrict__ Yt,          // [OUT][B]
    int K, int OUT)
{
    const int lane = threadIdx.x & 63;
    const int wv   = threadIdx.x >> 6;                 // 0..3
    const int b    = blockIdx.x * 64 + lane;
    const int i0   = blockIdx.y * 16 + wv * 4;

    const float* __restrict__ w0 = W + (i0 + 0) * K;
    const float* __restrict__ w1 = W + (i0 + 1) * K;
    const float* __restrict__ w2 = W + (i0 + 2) * K;
    const float* __restrict__ w3 = W + (i0 + 3) * K;

#define R2(a, c) (IS_MAX ? r2max((a), (c)) : r2min((a), (c)))

    float acc0, acc1, acc2, acc3;
    {   // peel k = 0..3 to initialize accumulators (no +-INF needed)
        float xa = Xt[0 * B_ALL + b];
        float xb = Xt[1 * B_ALL + b];
        float xc = Xt[2 * B_ALL + b];
        float xd = Xt[3 * B_ALL + b];
        acc0 = R2(R2(xa + w0[0], xb + w0[1]), R2(xc + w0[2], xd + w0[3]));
        acc1 = R2(R2(xa + w1[0], xb + w1[1]), R2(xc + w1[2], xd + w1[3]));
        acc2 = R2(R2(xa + w2[0], xb + w2[1]), R2(xc + w2[2], xd + w2[3]));
        acc3 = R2(R2(xa + w3[0], xb + w3[1]), R2(xc + w3[2], xd + w3[3]));
    }

#pragma unroll 2
    for (int k = 4; k < K; k += 4) {
        float xa = Xt[(k + 0) * B_ALL + b];
        float xb = Xt[(k + 1) * B_ALL + b];
        float xc = Xt[(k + 2) * B_ALL + b];
        float xd = Xt[(k + 3) * B_ALL + b];
        // min3/max3-friendly shapes: red(red(t0,t1),t2) and red(red(acc,tm),t3)
        {
            float tm = R2(R2(xa + w0[k + 0], xb + w0[k + 1]), xc + w0[k + 2]);
            acc0 = R2(R2(acc0, tm), xd + w0[k + 3]);
        }
        {
            float tm = R2(R2(xa + w1[k + 0], xb + w1[k + 1]), xc + w1[k + 2]);
            acc1 = R2(R2(acc1, tm), xd + w1[k + 3]);
        }
        {
            float tm = R2(R2(xa + w2[k + 0], xb + w2[k + 1]), xc + w2[k + 2]);
            acc2 = R2(R2(acc2, tm), xd + w2[k + 3]);
        }
        {
            float tm = R2(R2(xa + w3[k + 0], xb + w3[k + 1]), xc + w3[k + 2]);
            acc3 = R2(R2(acc3, tm), xd + w3[k + 3]);
        }
    }
#undef R2

    if (IS_MAX) {   // all max stages carry a bias in this network
        acc0 += bias[i0 + 0];
        acc1 += bias[i0 + 1];
        acc2 += bias[i0 + 2];
        acc3 += bias[i0 + 3];
    }
    if (COMBINE == 1) {
        acc0 = fminf(acc0, Et[(i0 + 0) * B_ALL + b]);
        acc1 = fminf(acc1, Et[(i0 + 1) * B_ALL + b]);
        acc2 = fminf(acc2, Et[(i0 + 2) * B_ALL + b]);
        acc3 = fminf(acc3, Et[(i0 + 3) * B_ALL + b]);
    } else if (COMBINE == 2) {
        acc0 = fmaxf(acc0, Et[(i0 + 0) * B_ALL + b]);
        acc1 = fmaxf(acc1, Et[(i0 + 1) * B_ALL + b]);
        acc2 = fmaxf(acc2, Et[(i0 + 2) * B_ALL + b]);
        acc3 = fmaxf(acc3, Et[(i0 + 3) * B_ALL + b]);
    }
    Yt[(i0 + 0) * B_ALL + b] = acc0;
    Yt[(i0 + 1) * B_ALL + b] = acc1;
    Yt[(i0 + 2) * B_ALL + b] = acc2;
    Yt[(i0 + 3) * B_ALL + b] = acc3;
}

// generic 64x64 LDS transpose: in [R][C] -> out [C][R]
__global__ __launch_bounds__(256) void transp(const float* __restrict__ in,
                                              float* __restrict__ out,
                                              int R, int C)
{
    __shared__ float s[64][65];
    const int tx = threadIdx.x & 63;
    const int ty = threadIdx.x >> 6;     // 0..3
    const int r0 = blockIdx.x * 64;
    const int c0 = blockIdx.y * 64;
#pragma unroll
    for (int r = 0; r < 64; r += 4)
        s[r + ty][tx] = in[(r0 + r + ty) * C + c0 + tx];
    __syncthreads();
#pragma unroll
    for (int r = 0; r < 64; r += 4)
        out[(c0 + r + ty) * R + r0 + tx] = s[tx][r + ty];
}

extern "C" void kernel_launch(void* const* d_in, const int* in_sizes, int n_in,
                              void* d_out, int out_size, void* d_ws, size_t ws_size,
                              hipStream_t stream) {
    const float* x      = (const float*)d_in[0];
    const float* l1_w1  = (const float*)d_in[1];
    const float* l1_w2  = (const float*)d_in[2];
    const float* l1_b2  = (const float*)d_in[3];
    const float* l2_w1  = (const float*)d_in[4];
    const float* l2_w2  = (const float*)d_in[5];
    const float* l2_b2  = (const float*)d_in[6];
    const float* l3_w1  = (const float*)d_in[7];
    const float* l3_w2  = (const float*)d_in[8];
    const float* l3_b2  = (const float*)d_in[9];
    const float* l4_w1  = (const float*)d_in[10];
    const float* l4_w2  = (const float*)d_in[11];
    const float* l4_b2  = (const float*)d_in[12];
    const float* l4_sw1 = (const float*)d_in[13];
    const float* l4_sw2 = (const float*)d_in[14];
    const float* l4_sb2 = (const float*)d_in[15];
    const float* sc_w1  = (const float*)d_in[16];
    const float* sc_w2  = (const float*)d_in[17];
    const float* sc_b2  = (const float*)d_in[18];
    (void)in_sizes; (void)n_in; (void)ws_size; (void)out_size;

    float* out = (float*)d_out;
    float* ws  = (float*)d_ws;

    const int B = 1024, IN = 256, OUT = 512;

    // workspace (floats): Xt [256*1024], M [256*1024], Xc [256*1024],
    //                     B0 [512*1024], B1 [512*1024]   => ~7.2 MB
    float* Xt = ws;
    float* M  = Xt + IN * B;
    float* Xc = M  + IN * B;
    float* B0 = Xc + IN * B;
    float* B1 = B0 + OUT * B;

    dim3 blk(256);
    dim3 gS(B / 64, IN / 16);    // 16 x 16 = 256 blocks (OUT=256)
    dim3 gL(B / 64, OUT / 16);   // 16 x 32 = 512 blocks (OUT=512)

    // x [1024][256] -> Xt [256][1024]
    transp<<<dim3(B / 64, IN / 64), blk, 0, stream>>>(x, Xt, B, IN);

    // layers 1-3 (IN->IN), shortcut = previous activation (elementwise min)
    tsemi<0, 0><<<gS, blk, 0, stream>>>(Xt, l1_w1, nullptr, nullptr, M,  IN, IN);
    tsemi<1, 1><<<gS, blk, 0, stream>>>(M,  l1_w2, l1_b2,   Xt,      Xc, IN, IN);
    tsemi<0, 0><<<gS, blk, 0, stream>>>(Xc, l2_w1, nullptr, nullptr, M,  IN, IN);
    tsemi<1, 1><<<gS, blk, 0, stream>>>(M,  l2_w2, l2_b2,   Xc,      Xc, IN, IN); // in-place combine
    tsemi<0, 0><<<gS, blk, 0, stream>>>(Xc, l3_w1, nullptr, nullptr, M,  IN, IN);
    tsemi<1, 1><<<gS, blk, 0, stream>>>(M,  l3_w2, l3_b2,   Xc,      Xc, IN, IN); // Xc = x3

    // layer 4 main path
    tsemi<0, 0><<<gL, blk, 0, stream>>>(Xc, l4_w1, nullptr, nullptr, B0, IN,  OUT);
    tsemi<1, 0><<<gL, blk, 0, stream>>>(B0, l4_w2, l4_b2,   nullptr, B1, OUT, OUT);
    // layer 4 shortcut path, min-combined with main (in place over B1)
    tsemi<0, 0><<<gL, blk, 0, stream>>>(Xc, l4_sw1, nullptr, nullptr, B0, IN,  OUT);
    tsemi<1, 1><<<gL, blk, 0, stream>>>(B0, l4_sw2, l4_sb2,  B1,      B1, OUT, OUT);

    // bottleneck shortcut from original x, max-combined (in place over B1)
    tsemi<0, 0><<<gL, blk, 0, stream>>>(Xt, sc_w1, nullptr, nullptr, B0, IN,  OUT);
    tsemi<1, 2><<<gL, blk, 0, stream>>>(B0, sc_w2, sc_b2,   B1,      B1, OUT, OUT);

    // B1 [512][1024] -> out [1024][512]
    transp<<<dim3(OUT / 64, B / 64), blk, 0, stream>>>(B1, out, OUT, B);
}

// Round 3
// 260.887 us; speedup vs baseline: 2.2444x; 1.2293x over previous
//
#include <hip/hip_runtime.h>
#include <math.h>

// Tropical bottleneck network, fp32.
// Activations live in "chunked transposed" layout: [K/4][1024][4] — for batch b,
// k-values k..k+3 are one float4 at ((k/4)*1024 + b). Lane = b: both loads and
// stores of activations are coalesced float4s. Weights W[i][k] are wave-uniform
// -> scalar (s_load_dwordx4) operands.
//
// tsemi: 512 threads = 8 waves = 4 row-waves x 2 K-halves (intra-block K-split,
// LDS min/max combine). Each block: 16 output rows x 64 batch.

#define BALL 1024

struct Job {
    const float* X;    // chunked [K/4][1024][4]
    const float* W;    // [rows][K] row-major
    const float* bias; // [rows] (max stages only)
    const float* E1;   // chunked, min-combine, or nullptr
    const float* E2;   // chunked, max-combine, or nullptr
    float* Y;          // chunked [rows/4][1024][4]
    int K;
};

template<int IS_MAX>
__device__ __forceinline__ void corequad(
    const float4* __restrict__ Xb,   // X4 + b ; stride BALL float4s per chunk
    const float4* __restrict__ w0, const float4* __restrict__ w1,
    const float4* __restrict__ w2, const float4* __restrict__ w3,
    int kcB, int kcE, float& a0, float& a1, float& a2, float& a3)
{
#define RD(x, y) (IS_MAX ? fmaxf((x), (y)) : fminf((x), (y)))
    {   // peel first chunk: initializes accumulators, no +-INF
        float4 xv = Xb[(size_t)kcB * BALL];
        float4 w;
        w = w0[kcB]; a0 = RD(RD(xv.x + w.x, xv.y + w.y), RD(xv.z + w.z, xv.w + w.w));
        w = w1[kcB]; a1 = RD(RD(xv.x + w.x, xv.y + w.y), RD(xv.z + w.z, xv.w + w.w));
        w = w2[kcB]; a2 = RD(RD(xv.x + w.x, xv.y + w.y), RD(xv.z + w.z, xv.w + w.w));
        w = w3[kcB]; a3 = RD(RD(xv.x + w.x, xv.y + w.y), RD(xv.z + w.z, xv.w + w.w));
    }
#pragma unroll 4
    for (int kc = kcB + 1; kc < kcE; ++kc) {
        float4 xv = Xb[(size_t)kc * BALL];
        float4 w;
        // chain shape fuses to v_min3/v_max3: (t0,t1,t2) then (m,t3,acc)
        w = w0[kc]; a0 = RD(RD(RD(RD(xv.x + w.x, xv.y + w.y), xv.z + w.z), xv.w + w.w), a0);
        w = w1[kc]; a1 = RD(RD(RD(RD(xv.x + w.x, xv.y + w.y), xv.z + w.z), xv.w + w.w), a1);
        w = w2[kc]; a2 = RD(RD(RD(RD(xv.x + w.x, xv.y + w.y), xv.z + w.z), xv.w + w.w), a2);
        w = w3[kc]; a3 = RD(RD(RD(RD(xv.x + w.x, xv.y + w.y), xv.z + w.z), xv.w + w.w), a3);
    }
#undef RD
}

// Two jobs per launch: blocks with blockIdx.y < nbyA run ja, the rest jb.
template<int IS_MAX>
__global__ __launch_bounds__(512) void tsemi(Job ja, Job jb, int nbyA)
{
    __shared__ float part[16][64];
    int by = blockIdx.y;
    Job j = ja;
    if (by >= nbyA) { j = jb; by -= nbyA; }

    const int lane = threadIdx.x & 63;
    const int wv   = threadIdx.x >> 6;   // 0..7
    const int rw   = wv & 3;             // row-wave
    const int half = wv >> 2;            // K-half
    const int b    = blockIdx.x * 64 + lane;
    const int i0   = by * 16 + rw * 4;

    const int KC  = j.K >> 2;
    const int kcB = half ? (KC >> 1) : 0;
    const int kcE = half ? KC : (KC >> 1);

    const float4* Xb = (const float4*)j.X + b;
    const float4* w0 = (const float4*)(j.W + (size_t)(i0 + 0) * j.K);
    const float4* w1 = (const float4*)(j.W + (size_t)(i0 + 1) * j.K);
    const float4* w2 = (const float4*)(j.W + (size_t)(i0 + 2) * j.K);
    const float4* w3 = (const float4*)(j.W + (size_t)(i0 + 3) * j.K);

    float a0, a1, a2, a3;
    corequad<IS_MAX>(Xb, w0, w1, w2, w3, kcB, kcE, a0, a1, a2, a3);

    if (half) {
        part[rw * 4 + 0][lane] = a0;
        part[rw * 4 + 1][lane] = a1;
        part[rw * 4 + 2][lane] = a2;
        part[rw * 4 + 3][lane] = a3;
    }
    __syncthreads();
    if (!half) {
#define RD(x, y) (IS_MAX ? fmaxf((x), (y)) : fminf((x), (y)))
        a0 = RD(a0, part[rw * 4 + 0][lane]);
        a1 = RD(a1, part[rw * 4 + 1][lane]);
        a2 = RD(a2, part[rw * 4 + 2][lane]);
        a3 = RD(a3, part[rw * 4 + 3][lane]);
#undef RD
        if (IS_MAX) {
            const float4 bb = ((const float4*)j.bias)[i0 >> 2];
            a0 += bb.x; a1 += bb.y; a2 += bb.z; a3 += bb.w;
        }
        if (j.E1) {
            float4 e = ((const float4*)j.E1)[(size_t)(i0 >> 2) * BALL + b];
            a0 = fminf(a0, e.x); a1 = fminf(a1, e.y);
            a2 = fminf(a2, e.z); a3 = fminf(a3, e.w);
        }
        if (j.E2) {
            float4 e = ((const float4*)j.E2)[(size_t)(i0 >> 2) * BALL + b];
            a0 = fmaxf(a0, e.x); a1 = fmaxf(a1, e.y);
            a2 = fmaxf(a2, e.z); a3 = fmaxf(a3, e.w);
        }
        ((float4*)j.Y)[(size_t)(i0 >> 2) * BALL + b] = make_float4(a0, a1, a2, a3);
    }
}

// x [1024][256] -> Xc chunked [64][1024][4]
__global__ __launch_bounds__(256) void t_in(const float* __restrict__ x,
                                            float* __restrict__ Xc)
{
    __shared__ float s[64][65];
    const int lane = threadIdx.x & 63;
    const int ty   = threadIdx.x >> 6;  // 0..3
    const int b0   = blockIdx.x * 64;
    const int k0   = blockIdx.y * 64;
#pragma unroll
    for (int r = ty; r < 64; r += 4)
        s[r][lane] = x[(size_t)(b0 + r) * 256 + k0 + lane];
    __syncthreads();
    float4* X4 = (float4*)Xc;
#pragma unroll
    for (int cc = 0; cc < 4; ++cc) {
        int c = ty * 4 + cc;  // chunk within tile, 0..15
        float4 v = make_float4(s[lane][c * 4 + 0], s[lane][c * 4 + 1],
                               s[lane][c * 4 + 2], s[lane][c * 4 + 3]);
        X4[(size_t)(k0 / 4 + c) * BALL + b0 + lane] = v;
    }
}

// Zc chunked [128][1024][4] (512 rows) -> out [1024][512]
__global__ __launch_bounds__(256) void t_out(const float* __restrict__ Zc,
                                             float* __restrict__ out)
{
    __shared__ float s[64][65];
    const int lane = threadIdx.x & 63;
    const int ty   = threadIdx.x >> 6;
    const int i0   = blockIdx.x * 64;
    const int b0   = blockIdx.y * 64;
    const float4* Z4 = (const float4*)Zc;
#pragma unroll
    for (int cc = 0; cc < 4; ++cc) {
        int c = ty * 4 + cc;
        float4 v = Z4[(size_t)(i0 / 4 + c) * BALL + b0 + lane];
        s[lane][c * 4 + 0] = v.x; s[lane][c * 4 + 1] = v.y;
        s[lane][c * 4 + 2] = v.z; s[lane][c * 4 + 3] = v.w;
    }
    __syncthreads();
#pragma unroll
    for (int r = ty; r < 64; r += 4)
        out[(size_t)(b0 + r) * 512 + i0 + lane] = s[r][lane];
}

extern "C" void kernel_launch(void* const* d_in, const int* in_sizes, int n_in,
                              void* d_out, int out_size, void* d_ws, size_t ws_size,
                              hipStream_t stream) {
    const float* x      = (const float*)d_in[0];
    const float* l1_w1  = (const float*)d_in[1];
    const float* l1_w2  = (const float*)d_in[2];
    const float* l1_b2  = (const float*)d_in[3];
    const float* l2_w1  = (const float*)d_in[4];
    const float* l2_w2  = (const float*)d_in[5];
    const float* l2_b2  = (const float*)d_in[6];
    const float* l3_w1  = (const float*)d_in[7];
    const float* l3_w2  = (const float*)d_in[8];
    const float* l3_b2  = (const float*)d_in[9];
    const float* l4_w1  = (const float*)d_in[10];
    const float* l4_w2  = (const float*)d_in[11];
    const float* l4_b2  = (const float*)d_in[12];
    const float* l4_sw1 = (const float*)d_in[13];
    const float* l4_sw2 = (const float*)d_in[14];
    const float* l4_sb2 = (const float*)d_in[15];
    const float* sc_w1  = (const float*)d_in[16];
    const float* sc_w2  = (const float*)d_in[17];
    const float* sc_b2  = (const float*)d_in[18];
    (void)in_sizes; (void)n_in; (void)ws_size; (void)out_size;

    float* out = (float*)d_out;
    float* ws  = (float*)d_ws;

    const int IN = 256, OUT = 512;

    // workspace (floats), 7.0 MB peak:
    float* Xc    = ws;             // 256K floats (1 MB)
    float* M     = ws + 262144;    // 1 MB
    float* A     = ws + 524288;    // 1 MB
    float* SC0   = ws + 786432;    // 2 MB (512K floats)
    float* SCout = ws + 1310720;   // 2 MB
    // aliases (lifetime-disjoint):
    float* X2 = Xc;                // after Xc dead (post stage 3)
    float* T  = SC0;               // after SC0 dead (post stage 3)
    float* Zf = ws;                // 2 MB over [Xc, M] (both dead by stage 11)
    float* O4 = out;               // d_out doubles as scratch for O4 (chunked)

    dim3 blk(512);
    Job nj{nullptr, nullptr, nullptr, nullptr, nullptr, nullptr, 0};

    // 1. x -> chunked Xc
    t_in<<<dim3(16, 4), 256, 0, stream>>>(x, Xc);

    // 2. merged min-plus: {Xc,l1_w1 -> M (256r)} + {Xc,sc_w1 -> SC0 (512r)}
    tsemi<0><<<dim3(16, 48), blk, 0, stream>>>(
        Job{Xc, l1_w1, nullptr, nullptr, nullptr, M, IN},
        Job{Xc, sc_w1, nullptr, nullptr, nullptr, SC0, IN}, 16);

    // 3. merged max-plus: {M,l1_w2,b2, min Xc -> A} + {SC0,sc_w2,sc_b2 -> SCout}
    tsemi<1><<<dim3(16, 48), blk, 0, stream>>>(
        Job{M, l1_w2, l1_b2, Xc, nullptr, A, IN},
        Job{SC0, sc_w2, sc_b2, nullptr, nullptr, SCout, OUT}, 16);

    // 4-7. layers 2 and 3
    tsemi<0><<<dim3(16, 16), blk, 0, stream>>>(
        Job{A, l2_w1, nullptr, nullptr, nullptr, M, IN}, nj, 16);
    tsemi<1><<<dim3(16, 16), blk, 0, stream>>>(
        Job{M, l2_w2, l2_b2, A, nullptr, X2, IN}, nj, 16);
    tsemi<0><<<dim3(16, 16), blk, 0, stream>>>(
        Job{X2, l3_w1, nullptr, nullptr, nullptr, M, IN}, nj, 16);
    tsemi<1><<<dim3(16, 16), blk, 0, stream>>>(
        Job{M, l3_w2, l3_b2, X2, nullptr, A, IN}, nj, 16);   // A = x3

    // 8-11. layer 4 (main then shortcut path; T reused, O4 staged in d_out)
    tsemi<0><<<dim3(16, 32), blk, 0, stream>>>(
        Job{A, l4_w1, nullptr, nullptr, nullptr, T, IN}, nj, 32);
    tsemi<1><<<dim3(16, 32), blk, 0, stream>>>(
        Job{T, l4_w2, l4_b2, nullptr, nullptr, O4, OUT}, nj, 32);
    tsemi<0><<<dim3(16, 32), blk, 0, stream>>>(
        Job{A, l4_sw1, nullptr, nullptr, nullptr, T, IN}, nj, 32);
    // Zf = max( min( maxbplus(T,l4_sw2,sb2), O4 ), SCout )
    tsemi<1><<<dim3(16, 32), blk, 0, stream>>>(
        Job{T, l4_sw2, l4_sb2, O4, SCout, Zf, OUT}, nj, 32);

    // 12. un-transpose Zf -> out
    t_out<<<dim3(8, 16), 256, 0, stream>>>(Zf, out);
}